// Round 1
// baseline (1244.214 us; speedup 1.0000x reference)
//
#include <hip/hip_runtime.h>
#include <math.h>

#define T_LEN 512
#define H_DIM 50

__device__ __forceinline__ float sigmoid_f(float v) {
    return 1.0f / (1.0f + __expf(-v));
}
// tanh via exp2-based fast exp; saturates correctly for large |v| (exp->inf/0).
__device__ __forceinline__ float tanh_f(float v) {
    return 1.0f - 2.0f / (__expf(2.0f * v) + 1.0f);
}

// One block = one batch element for the entire T=512 recurrence.
// Lane u (< 50) owns hidden unit u: holds W_hh rows {u, 50+u, 100+u, 150+u}
// (i,f,g,o) in 200 persistent VGPRs, plus c[u] in a register. h is shared via
// double-buffered LDS (broadcast ds_read_b128 reads). Lanes 50..63 compute
// garbage on zeroed weights and never write.
__global__ __launch_bounds__(64, 2) void lstm_fused(
    const float* __restrict__ x,
    const float* __restrict__ W_ih,
    const float* __restrict__ W_hh,
    const float* __restrict__ b_ih,
    const float* __restrict__ b_hh,
    const float* __restrict__ W_fc,
    const float* __restrict__ b_fc,
    float* __restrict__ out)
{
    const int b = blockIdx.x;
    const int u = threadIdx.x;            // 0..63; active unit if u < 50
    const bool act = (u < H_DIM);

    __shared__ float xs[T_LEN];
    __shared__ float hs[2][52];           // row stride 52 floats = 208B (16B-aligned)

    // Stage the whole input sequence for this batch element (I=1): 512 floats.
    {
        const float4* xb4 = reinterpret_cast<const float4*>(x + (size_t)b * T_LEN);
        float4* xs4 = reinterpret_cast<float4*>(xs);
        xs4[u]      = xb4[u];
        xs4[u + 64] = xb4[u + 64];
    }
    if (u < 52) { hs[0][u] = 0.0f; hs[1][u] = 0.0f; }

    // Load per-thread weights (one-time). Inactive lanes get zeros via select
    // from a safe in-bounds row.
    float W[4][H_DIM];
    float wih[4], bias[4];
    #pragma unroll
    for (int g = 0; g < 4; ++g) {
        const int row = g * H_DIM + (act ? u : 0);   // always in [0,200)
        const float wv = W_ih[row];                  // W_ih is [200][1]
        const float bv = b_ih[row] + b_hh[row];
        wih[g]  = act ? wv : 0.0f;
        bias[g] = act ? bv : 0.0f;
        const float2* wr = reinterpret_cast<const float2*>(W_hh + (size_t)row * H_DIM);
        #pragma unroll
        for (int j2 = 0; j2 < H_DIM / 2; ++j2) {     // 25 x float2 (8B-aligned: row*200B)
            const float2 w2 = wr[j2];
            W[g][2 * j2]     = act ? w2.x : 0.0f;
            W[g][2 * j2 + 1] = act ? w2.y : 0.0f;
        }
    }

    float c = 0.0f;
    __syncthreads();

    for (int t = 0; t < T_LEN; ++t) {
        const int cur = t & 1;
        const float xv = xs[t];

        float a[4];
        #pragma unroll
        for (int g = 0; g < 4; ++g) a[g] = __fmaf_rn(xv, wih[g], bias[g]);

        // gates += W_hh[row] . h   (h broadcast from LDS, 12x b128 + 1x b64)
        #pragma unroll
        for (int q = 0; q < 12; ++q) {
            const float4 h4 = *reinterpret_cast<const float4*>(&hs[cur][4 * q]);
            #pragma unroll
            for (int g = 0; g < 4; ++g) {
                a[g] = __fmaf_rn(W[g][4 * q + 0], h4.x, a[g]);
                a[g] = __fmaf_rn(W[g][4 * q + 1], h4.y, a[g]);
                a[g] = __fmaf_rn(W[g][4 * q + 2], h4.z, a[g]);
                a[g] = __fmaf_rn(W[g][4 * q + 3], h4.w, a[g]);
            }
        }
        {
            const float2 h2 = *reinterpret_cast<const float2*>(&hs[cur][48]);
            #pragma unroll
            for (int g = 0; g < 4; ++g) {
                a[g] = __fmaf_rn(W[g][48], h2.x, a[g]);
                a[g] = __fmaf_rn(W[g][49], h2.y, a[g]);
            }
        }

        // LSTM cell update (torch gate order i,f,g,o)
        const float ig = sigmoid_f(a[0]);
        const float fg = sigmoid_f(a[1]);
        const float gg = tanh_f(a[2]);
        const float og = sigmoid_f(a[3]);
        c = __fmaf_rn(fg, c, ig * gg);
        const float hv = og * tanh_f(c);

        if (act) hs[cur ^ 1][u] = hv;
        __syncthreads();   // one barrier/step; double-buffer makes it sufficient
    }

    // Final h is in hs[0] (t=511 wrote buffer 0). out[b] = h . W_fc + b_fc
    float part = 0.0f;
    if (act) part = hs[0][u] * W_fc[u];
    #pragma unroll
    for (int off = 32; off > 0; off >>= 1) part += __shfl_down(part, off);
    if (u == 0) out[b] = part + b_fc[0];
}

extern "C" void kernel_launch(void* const* d_in, const int* in_sizes, int n_in,
                              void* d_out, int out_size, void* d_ws, size_t ws_size,
                              hipStream_t stream) {
    const float* x    = (const float*)d_in[0];
    const float* W_ih = (const float*)d_in[1];
    const float* W_hh = (const float*)d_in[2];
    const float* b_ih = (const float*)d_in[3];
    const float* b_hh = (const float*)d_in[4];
    const float* W_fc = (const float*)d_in[5];
    const float* b_fc = (const float*)d_in[6];
    float* out = (float*)d_out;

    const int B = in_sizes[0] / T_LEN;   // 4096
    lstm_fused<<<dim3(B), dim3(64), 0, stream>>>(x, W_ih, W_hh, b_ih, b_hh, W_fc, b_fc, out);
}